// Round 11
// baseline (262.654 us; speedup 1.0000x reference)
//
#include <hip/hip_runtime.h>

#define TOK     50176
#define NQKV    1152
#define DMODEL  384
#define HW      3136
#define NWIN    1024

typedef __bf16 bf16x8 __attribute__((ext_vector_type(8)));
typedef float  f32x4  __attribute__((ext_vector_type(4)));

__device__ __forceinline__ __bf16 f2bf(float f) {            // round-to-nearest-even
  unsigned u = __float_as_uint(f);
  u += 0x7fffu + ((u >> 16) & 1u);
  unsigned short s = (unsigned short)(u >> 16);
  return __builtin_bit_cast(__bf16, s);
}
__device__ __forceinline__ unsigned short f2bfu(float f) {
  return __builtin_bit_cast(unsigned short, f2bf(f));
}
__device__ __forceinline__ float bf2f(__bf16 b) {
  return __uint_as_float(((unsigned)__builtin_bit_cast(unsigned short, b)) << 16);
}
__device__ __forceinline__ void gload_lds16(const void* g, void* l) {
  __builtin_amdgcn_global_load_lds(
      (const __attribute__((address_space(1))) unsigned int*)g,
      (__attribute__((address_space(3))) unsigned int*)l, 16, 0, 0);
}

// ---------------------------------------------------------------------------
// Gather x (16,384,56,56) fp32 -> Xw (50176, 384) bf16 token-major.
// ---------------------------------------------------------------------------
__global__ __launch_bounds__(256) void gather_x(const float* __restrict__ x,
                                                __bf16* __restrict__ Xw) {
  __shared__ __bf16 lt[392 * 48];
  const int ct = blockIdx.x, hr = blockIdx.y, b = blockIdx.z;
  const int tid = threadIdx.x;
  const float* xb = x + ((size_t)(b * 384 + ct * 48)) * HW + hr * 7 * 56;

  for (int u = tid; u < 48 * 7 * 14; u += 256) {
    const int ch = u / 98, rem = u % 98;
    const int h7 = rem / 14, w4 = rem % 14;
    const float4 v = *(const float4*)&xb[(size_t)ch * HW + h7 * 56 + 4 * w4];
    const float vv[4] = {v.x, v.y, v.z, v.w};
#pragma unroll
    for (int e = 0; e < 4; ++e) {
      const int w = 4 * w4 + e;
      const int t = (w / 7) * 49 + h7 * 7 + (w % 7);
      lt[t * 48 + ch] = f2bf(vv[e]);
    }
  }
  __syncthreads();

  const size_t tokbase = (size_t)(b * 64 + hr * 8) * 49;
  for (int u = tid; u < 392 * 6; u += 256) {
    const int t = u / 6, c6 = u % 6;
    const bf16x8 vv = *(const bf16x8*)&lt[t * 48 + 8 * c6];
    *(bf16x8*)&Xw[(tokbase + t) * DMODEL + ct * 48 + 8 * c6] = vv;
  }
}

// ---------------------------------------------------------------------------
// Unscatter: attnP (50176,384) bf16 token-major -> out (16,384,56,56) fp32.
// ---------------------------------------------------------------------------
__global__ __launch_bounds__(256) void unscatter(const __bf16* __restrict__ P,
                                                 float* __restrict__ out) {
  __shared__ __bf16 lt[392 * 48];
  const int ct = blockIdx.x, hr = blockIdx.y, b = blockIdx.z;
  const int tid = threadIdx.x;
  const size_t tokbase = (size_t)(b * 64 + hr * 8) * 49;

  for (int u = tid; u < 392 * 6; u += 256) {
    const int t = u / 6, c6 = u % 6;
    *(bf16x8*)&lt[t * 48 + 8 * c6] =
        *(const bf16x8*)&P[(tokbase + t) * DMODEL + ct * 48 + 8 * c6];
  }
  __syncthreads();

  float* ob = out + ((size_t)(b * 384 + ct * 48)) * HW + hr * 7 * 56;
  for (int u = tid; u < 48 * 98; u += 256) {
    const int ch = u / 98, rem = u % 98;
    const int h7 = rem / 14, w4 = rem % 14;
    float4 o;
    float* oo = (float*)&o;
#pragma unroll
    for (int e = 0; e < 4; ++e) {
      const int w = 4 * w4 + e;
      const int t = (w / 7) * 49 + h7 * 7 + (w % 7);
      oo[e] = bf2f(lt[t * 48 + ch]);
    }
    *(float4*)&ob[(size_t)ch * HW + h7 * 56 + 4 * w4] = o;
  }
}

// Transpose+convert weights: WqkvT (1152,384) bf16, WprojT (384,384) bf16.
__global__ void conv_w(const float* __restrict__ Wqkv, const float* __restrict__ Wproj,
                       __bf16* __restrict__ WqkvT, __bf16* __restrict__ WprojT) {
  const int idx = blockIdx.x * 256 + threadIdx.x;
  if (idx < DMODEL * NQKV) {
    const int k = idx / NQKV, n = idx % NQKV;
    WqkvT[(size_t)n * DMODEL + k] = f2bf(Wqkv[idx]);
  }
  if (idx < DMODEL * DMODEL) {
    const int k = idx / DMODEL, n = idx % DMODEL;
    WprojT[(size_t)n * DMODEL + k] = f2bf(Wproj[idx]);
  }
}

// ---------------------------------------------------------------------------
// bf16 MFMA GEMM, 256x128 tile, BK=32, 256 threads = 4 waves, per-wave
// 128x64 output: 12 ds_read_b128 feed 32 MFMAs per wave per K-step
// (0.034 LDS-B/FLOP vs 0.042 of the 64x64 blocking). Double-buffered LDS
// via global_load_lds, 2-phase __syncthreads loop. No min-wave bound
// (~210 regs -> 2 waves/SIMD naturally, no spill). T5 setprio around the
// MFMA cluster. LDS-staged epilogue: acc -> LDS [64][70]/wave -> 16B/lane
// contiguous global stores (deterministic write merging, no partial-line
// amplification). Bijective XCD-chunk swizzle.
// ---------------------------------------------------------------------------
__global__ __launch_bounds__(256) void gemm256(const __bf16* __restrict__ A,
                                               const __bf16* __restrict__ BT,
                                               const float* __restrict__ bias,
                                               __bf16* __restrict__ Cout, int Ncols) {
  // stage: 2 x (256x32 A + 128x32 B) = 49152 B; epilogue overlay 4x64x70x2 = 35840 B
  __shared__ __align__(16) __bf16 sm[2 * (256 * 32 + 128 * 32)];
  const int tid  = threadIdx.x;
  const int lane = tid & 63;
  const int wid  = tid >> 6;

  // bijective XCD-chunked swizzle (m204 variant; works for any nwg)
  const int nwg  = gridDim.x * gridDim.y;
  const int orig = blockIdx.y * gridDim.x + blockIdx.x;
  const int q    = nwg >> 3, r = nwg & 7;
  const int xcd  = orig & 7, pos = orig >> 3;
  const int start = (xcd < r) ? xcd * (q + 1) : r * (q + 1) + (xcd - r) * q;
  const int w    = start + pos;
  const int bn   = (w % gridDim.x) << 7;   // N tile: 128
  const int bm   = (w / gridDim.x) << 8;   // M tile: 256

  // staging sources: 256 threads cover 64 rows x 32 cols per instruction
  const __bf16* a0 = A  + (size_t)(bm +       (tid >> 2)) * DMODEL + ((tid & 3) << 3);
  const __bf16* a1 = A  + (size_t)(bm +  64 + (tid >> 2)) * DMODEL + ((tid & 3) << 3);
  const __bf16* a2 = A  + (size_t)(bm + 128 + (tid >> 2)) * DMODEL + ((tid & 3) << 3);
  const __bf16* a3 = A  + (size_t)(bm + 192 + (tid >> 2)) * DMODEL + ((tid & 3) << 3);
  const __bf16* b0 = BT + (size_t)(bn +       (tid >> 2)) * DMODEL + ((tid & 3) << 3);
  const __bf16* b1 = BT + (size_t)(bn +  64 + (tid >> 2)) * DMODEL + ((tid & 3) << 3);

  const int wm = (wid >> 1) << 7;   // 0,128
  const int wn = (wid & 1) << 6;    // 0,64
  const int lrow = lane & 15;
  const int lk8  = (lane >> 4) << 3;

  f32x4 acc[4][8] = {};   // acc[j][i]: j = channel frag (4), i = token frag (8)

  auto stage = [&](int buf, int kt) {
    const int koff = kt << 5;
    __bf16* As = sm + buf * (384 * 32);
    __bf16* Bs = As + 256 * 32;
    gload_lds16(a0 + koff, As + (wid << 9));
    gload_lds16(a1 + koff, As + 2048 + (wid << 9));
    gload_lds16(a2 + koff, As + 4096 + (wid << 9));
    gload_lds16(a3 + koff, As + 6144 + (wid << 9));
    gload_lds16(b0 + koff, Bs + (wid << 9));
    gload_lds16(b1 + koff, Bs + 2048 + (wid << 9));
  };

  stage(0, 0);
#pragma unroll 1
  for (int kt = 0; kt < 12; ++kt) {
    __syncthreads();                       // drains vmcnt -> buf[kt&1] ready
    if (kt + 1 < 12) stage((kt + 1) & 1, kt + 1);
    const __bf16* As = sm + (kt & 1) * (384 * 32);
    const __bf16* Bs = As + 256 * 32;
    const __bf16* pA = As + (wm + lrow) * 32 + lk8;
    const __bf16* pB = Bs + (wn + lrow) * 32 + lk8;
    bf16x8 av[8], bv[4];
#pragma unroll
    for (int i = 0; i < 8; ++i) av[i] = *(const bf16x8*)(pA + i * 16 * 32);
#pragma unroll
    for (int j = 0; j < 4; ++j) bv[j] = *(const bf16x8*)(pB + j * 16 * 32);
    __builtin_amdgcn_s_setprio(1);
#pragma unroll
    for (int i = 0; i < 8; ++i)
#pragma unroll
      for (int j = 0; j < 4; ++j)
        acc[j][i] = __builtin_amdgcn_mfma_f32_16x16x32_bf16(bv[j], av[i], acc[j][i], 0, 0, 0);
    __builtin_amdgcn_s_setprio(0);
  }

  // ---------------- LDS-staged epilogue ----------------
  __syncthreads();                          // all stage reads done; reuse sm
  const int lr = lane & 15, g = lane >> 4;
  __bf16* epi = sm + wid * (64 * 70);       // per-wave [64][70] bf16

  float4 b4[4];
#pragma unroll
  for (int j = 0; j < 4; ++j)
    b4[j] = *(const float4*)&bias[bn + wn + (g << 2) + 16 * j];

  const int rrow = lane >> 3;               // 0..7
  const int rcol = (lane & 7) << 3;         // 0..56

#pragma unroll
  for (int half = 0; half < 2; ++half) {
#pragma unroll
    for (int j = 0; j < 4; ++j)
#pragma unroll
      for (int i = 0; i < 4; ++i) {
        const int ii = (half << 2) + i;
        ushort4 pk;
        pk.x = f2bfu(acc[j][ii][0] + b4[j].x);
        pk.y = f2bfu(acc[j][ii][1] + b4[j].y);
        pk.z = f2bfu(acc[j][ii][2] + b4[j].z);
        pk.w = f2bfu(acc[j][ii][3] + b4[j].w);
        *(ushort4*)&epi[(lr + (i << 4)) * 70 + (g << 2) + (j << 4)] = pk;
      }
    asm volatile("s_waitcnt lgkmcnt(0)" ::: "memory");
#pragma unroll
    for (int p = 0; p < 8; ++p) {
      const int trow = (p << 3) + rrow;     // 0..63 within half
      const bf16x8 v = *(const bf16x8*)&epi[trow * 70 + rcol];
      *(bf16x8*)&Cout[(size_t)(bm + wm + (half << 6) + trow) * Ncols + bn + wn + rcol] = v;
    }
    asm volatile("s_waitcnt lgkmcnt(0)" ::: "memory");  // reads done before half-1 overwrite
  }
}

// ---------------------------------------------------------------------------
// MFMA attention: one wave per (window, head). Pad 49 -> 64. (unchanged)
// ---------------------------------------------------------------------------
__global__ __launch_bounds__(64) void attn_mfma(const __bf16* __restrict__ qkv,
                                                __bf16* __restrict__ attnO) {
  __shared__ __align__(16) __bf16 lds[96 * 72];
  __bf16* p_lds = lds;
  __bf16* vt    = lds + 64 * 72;

  const int lane = threadIdx.x;
  const int win  = blockIdx.x;
  const int h    = blockIdx.y;
  const int lr = lane & 15, g = lane >> 4;
  const size_t rowbase = (size_t)win * 49;

  int rr[4];
#pragma unroll
  for (int f = 0; f < 4; ++f) rr[f] = (16 * f + lr > 48) ? 48 : (16 * f + lr);

  const int co = h * 32 + 8 * g;

  bf16x8 av[4], bv[4];
#pragma unroll
  for (int f = 0; f < 4; ++f) {
    const __bf16* rp = qkv + (rowbase + rr[f]) * NQKV + co;
    av[f] = *(const bf16x8*)(rp + 384);
    bv[f] = *(const bf16x8*)(rp);
  }

  ushort4 vreg[7];
#pragma unroll
  for (int u = 0; u < 7; ++u) {
    const int unit = lane + (u << 6);
    if (unit < 392) {
      const int k = unit >> 3, dq = unit & 7;
      vreg[u] = *(const ushort4*)(qkv + (rowbase + k) * NQKV + 768 + h * 32 + 4 * dq);
    }
  }

  f32x4 acc[4][4] = {};
#pragma unroll
  for (int i = 0; i < 4; ++i)
#pragma unroll
    for (int j = 0; j < 4; ++j)
      acc[i][j] = __builtin_amdgcn_mfma_f32_16x16x32_bf16(av[i], bv[j], acc[i][j], 0, 0, 0);

  const float scale = 0.17677669529663687f;
#pragma unroll
  for (int i = 0; i < 4; ++i)
#pragma unroll
    for (int j = 0; j < 4; ++j)
#pragma unroll
      for (int r = 0; r < 4; ++r) {
        float v = acc[i][j][r] * scale;
        if (i == 3 && (4 * g + r) != 0) v = -1e30f;
        acc[i][j][r] = v;
      }

#pragma unroll
  for (int u = 0; u < 7; ++u) {
    const int unit = lane + (u << 6);
    if (unit < 392) {
      const int k = unit >> 3, dq = unit & 7;
      const ushort4 vv = vreg[u];
      vt[(4 * dq + 0) * 72 + k] = __builtin_bit_cast(__bf16, vv.x);
      vt[(4 * dq + 1) * 72 + k] = __builtin_bit_cast(__bf16, vv.y);
      vt[(4 * dq + 2) * 72 + k] = __builtin_bit_cast(__bf16, vv.z);
      vt[(4 * dq + 3) * 72 + k] = __builtin_bit_cast(__bf16, vv.w);
    }
  }

#pragma unroll
  for (int j = 0; j < 4; ++j) {
    float mx = -1e30f;
#pragma unroll
    for (int i = 0; i < 4; ++i)
#pragma unroll
      for (int r = 0; r < 4; ++r) mx = fmaxf(mx, acc[i][j][r]);
    mx = fmaxf(mx, __shfl_xor(mx, 16));
    mx = fmaxf(mx, __shfl_xor(mx, 32));
    float sum = 0.f;
#pragma unroll
    for (int i = 0; i < 4; ++i)
#pragma unroll
      for (int r = 0; r < 4; ++r) {
        const float e = __expf(acc[i][j][r] - mx);
        acc[i][j][r] = e;
        sum += e;
      }
    sum += __shfl_xor(sum, 16);
    sum += __shfl_xor(sum, 32);
    const float inv = 1.f / sum;
#pragma unroll
    for (int i = 0; i < 4; ++i) {
      ushort4 pk;
      pk.x = f2bfu(acc[i][j][0] * inv);
      pk.y = f2bfu(acc[i][j][1] * inv);
      pk.z = f2bfu(acc[i][j][2] * inv);
      pk.w = f2bfu(acc[i][j][3] * inv);
      *(ushort4*)&p_lds[(16 * j + lr) * 72 + 16 * i + 4 * g] = pk;
    }
  }

  f32x4 o[2][4] = {};
#pragma unroll
  for (int ks = 0; ks < 2; ++ks) {
    bf16x8 a2[2], b2[4];
#pragma unroll
    for (int i2 = 0; i2 < 2; ++i2)
      a2[i2] = *(const bf16x8*)&vt[(16 * i2 + lr) * 72 + 32 * ks + 8 * g];
#pragma unroll
    for (int j2 = 0; j2 < 4; ++j2)
      b2[j2] = *(const bf16x8*)&p_lds[(16 * j2 + lr) * 72 + 32 * ks + 8 * g];
#pragma unroll
    for (int i2 = 0; i2 < 2; ++i2)
#pragma unroll
      for (int j2 = 0; j2 < 4; ++j2)
        o[i2][j2] = __builtin_amdgcn_mfma_f32_16x16x32_bf16(a2[i2], b2[j2], o[i2][j2], 0, 0, 0);
  }

#pragma unroll
  for (int j2 = 0; j2 < 4; ++j2) {
    const int q = 16 * j2 + lr;
    if (q <= 48) {
#pragma unroll
      for (int i2 = 0; i2 < 2; ++i2) {
        ushort4 ok;
        ok.x = f2bfu(o[i2][j2][0]);
        ok.y = f2bfu(o[i2][j2][1]);
        ok.z = f2bfu(o[i2][j2][2]);
        ok.w = f2bfu(o[i2][j2][3]);
        *(ushort4*)&attnO[(rowbase + q) * DMODEL + h * 32 + 16 * i2 + 4 * g] = ok;
      }
    }
  }
}

extern "C" void kernel_launch(void* const* d_in, const int* in_sizes, int n_in,
                              void* d_out, int out_size, void* d_ws, size_t ws_size,
                              hipStream_t stream) {
  const float* x     = (const float*)d_in[0];
  const float* Wqkv  = (const float*)d_in[1];
  const float* bqkv  = (const float*)d_in[2];
  const float* Wproj = (const float*)d_in[3];
  const float* bproj = (const float*)d_in[4];
  float* out = (float*)d_out;

  char* ws = (char*)d_ws;
  __bf16* Xw     = (__bf16*)ws;  ws += (size_t)TOK * DMODEL * 2;   // 38.5 MB
  __bf16* qkvb   = (__bf16*)ws;  ws += (size_t)TOK * NQKV * 2;     // 115.6 MB
  __bf16* attnO  = (__bf16*)ws;  ws += (size_t)TOK * DMODEL * 2;   // 38.5 MB
  __bf16* attnP  = (__bf16*)ws;  ws += (size_t)TOK * DMODEL * 2;   // 38.5 MB
  __bf16* WqkvT  = (__bf16*)ws;  ws += (size_t)NQKV * DMODEL * 2;
  __bf16* WprojT = (__bf16*)ws;

  gather_x<<<dim3(8, 8, 16), 256, 0, stream>>>(x, Xw);
  conv_w<<<1728, 256, 0, stream>>>(Wqkv, Wproj, WqkvT, WprojT);
  gemm256<<<dim3(NQKV / 128, TOK / 256), 256, 0, stream>>>(Xw, WqkvT, bqkv, qkvb, NQKV);
  attn_mfma<<<dim3(NWIN, 12), 64, 0, stream>>>(qkvb, attnO);
  gemm256<<<dim3(DMODEL / 128, TOK / 256), 256, 0, stream>>>(attnO, WprojT, bproj, attnP, DMODEL);
  unscatter<<<dim3(8, 8, 16), 256, 0, stream>>>(attnP, out);
}

// Round 12
// 228.429 us; speedup vs baseline: 1.1498x; 1.1498x over previous
//
#include <hip/hip_runtime.h>

#define TOK     50176
#define NQKV    1152
#define DMODEL  384
#define HW      3136
#define NWIN    1024

typedef __bf16 bf16x8 __attribute__((ext_vector_type(8)));
typedef float  f32x4  __attribute__((ext_vector_type(4)));

__device__ __forceinline__ __bf16 f2bf(float f) {            // round-to-nearest-even
  unsigned u = __float_as_uint(f);
  u += 0x7fffu + ((u >> 16) & 1u);
  unsigned short s = (unsigned short)(u >> 16);
  return __builtin_bit_cast(__bf16, s);
}
__device__ __forceinline__ unsigned short f2bfu(float f) {
  return __builtin_bit_cast(unsigned short, f2bf(f));
}
__device__ __forceinline__ float bf2f(__bf16 b) {
  return __uint_as_float(((unsigned)__builtin_bit_cast(unsigned short, b)) << 16);
}
__device__ __forceinline__ void gload_lds16(const void* g, void* l) {
  __builtin_amdgcn_global_load_lds(
      (const __attribute__((address_space(1))) unsigned int*)g,
      (__attribute__((address_space(3))) unsigned int*)l, 16, 0, 0);
}

// ---------------------------------------------------------------------------
// Gather x (16,384,56,56) fp32 -> Xw (50176, 384) bf16 token-major.
// ---------------------------------------------------------------------------
__global__ __launch_bounds__(256) void gather_x(const float* __restrict__ x,
                                                __bf16* __restrict__ Xw) {
  __shared__ __bf16 lt[392 * 48];
  const int ct = blockIdx.x, hr = blockIdx.y, b = blockIdx.z;
  const int tid = threadIdx.x;
  const float* xb = x + ((size_t)(b * 384 + ct * 48)) * HW + hr * 7 * 56;

  for (int u = tid; u < 48 * 7 * 14; u += 256) {
    const int ch = u / 98, rem = u % 98;
    const int h7 = rem / 14, w4 = rem % 14;
    const float4 v = *(const float4*)&xb[(size_t)ch * HW + h7 * 56 + 4 * w4];
    const float vv[4] = {v.x, v.y, v.z, v.w};
#pragma unroll
    for (int e = 0; e < 4; ++e) {
      const int w = 4 * w4 + e;
      const int t = (w / 7) * 49 + h7 * 7 + (w % 7);
      lt[t * 48 + ch] = f2bf(vv[e]);
    }
  }
  __syncthreads();

  const size_t tokbase = (size_t)(b * 64 + hr * 8) * 49;
  for (int u = tid; u < 392 * 6; u += 256) {
    const int t = u / 6, c6 = u % 6;
    const bf16x8 vv = *(const bf16x8*)&lt[t * 48 + 8 * c6];
    *(bf16x8*)&Xw[(tokbase + t) * DMODEL + ct * 48 + 8 * c6] = vv;
  }
}

// ---------------------------------------------------------------------------
// Unscatter: attnP (50176,384) bf16 token-major -> out (16,384,56,56) fp32.
// ---------------------------------------------------------------------------
__global__ __launch_bounds__(256) void unscatter(const __bf16* __restrict__ P,
                                                 float* __restrict__ out) {
  __shared__ __bf16 lt[392 * 48];
  const int ct = blockIdx.x, hr = blockIdx.y, b = blockIdx.z;
  const int tid = threadIdx.x;
  const size_t tokbase = (size_t)(b * 64 + hr * 8) * 49;

  for (int u = tid; u < 392 * 6; u += 256) {
    const int t = u / 6, c6 = u % 6;
    *(bf16x8*)&lt[t * 48 + 8 * c6] =
        *(const bf16x8*)&P[(tokbase + t) * DMODEL + ct * 48 + 8 * c6];
  }
  __syncthreads();

  float* ob = out + ((size_t)(b * 384 + ct * 48)) * HW + hr * 7 * 56;
  for (int u = tid; u < 48 * 98; u += 256) {
    const int ch = u / 98, rem = u % 98;
    const int h7 = rem / 14, w4 = rem % 14;
    float4 o;
    float* oo = (float*)&o;
#pragma unroll
    for (int e = 0; e < 4; ++e) {
      const int w = 4 * w4 + e;
      const int t = (w / 7) * 49 + h7 * 7 + (w % 7);
      oo[e] = bf2f(lt[t * 48 + ch]);
    }
    *(float4*)&ob[(size_t)ch * HW + h7 * 56 + 4 * w4] = o;
  }
}

// Transpose+convert weights: WqkvT (1152,384) bf16, WprojT (384,384) bf16.
__global__ void conv_w(const float* __restrict__ Wqkv, const float* __restrict__ Wproj,
                       __bf16* __restrict__ WqkvT, __bf16* __restrict__ WprojT) {
  const int idx = blockIdx.x * 256 + threadIdx.x;
  if (idx < DMODEL * NQKV) {
    const int k = idx / NQKV, n = idx % NQKV;
    WqkvT[(size_t)n * DMODEL + k] = f2bf(Wqkv[idx]);
  }
  if (idx < DMODEL * DMODEL) {
    const int k = idx / DMODEL, n = idx % DMODEL;
    WprojT[(size_t)n * DMODEL + k] = f2bf(Wproj[idx]);
  }
}

// ---------------------------------------------------------------------------
// bf16 MFMA GEMM, 256x128 tile, BK=32, 512 threads (8 waves: 4M x 2N, each
// wave 64x64 -- the proven r6 geometry). T3+T4 combo: per K-step TWO phases
// {stage-issue || ds_read || 8 MFMA || barrier}, 3 LDS buffers, depth-2
// prefetch, step-boundary s_waitcnt vmcnt(3) (next tile's 3 stage loads
// stay in flight across barriers -- no drain-to-0). T5 setprio around MFMA.
// sched_barrier(0) pins at every barrier (hipcc hoists reg-only MFMA past
// inline-asm waits otherwise). Tail stages wrapped tiles into already-
// consumed buffers to keep vmcnt arithmetic uniform (r7-verified).
// Bijective XCD-chunk swizzle. Transposed accumulator -> ushort4 stores.
// ---------------------------------------------------------------------------
__global__ __launch_bounds__(512) void gemm256(const __bf16* __restrict__ A,
                                               const __bf16* __restrict__ BT,
                                               const float* __restrict__ bias,
                                               __bf16* __restrict__ Cout, int Ncols) {
  __shared__ __align__(16) __bf16 As[3][256 * 32];
  __shared__ __align__(16) __bf16 Bs[3][128 * 32];
  const int tid  = threadIdx.x;
  const int lane = tid & 63;
  const int wid  = tid >> 6;

  // bijective XCD-chunked swizzle (m204 variant; works for any nwg)
  const int nwg  = gridDim.x * gridDim.y;
  const int orig = blockIdx.y * gridDim.x + blockIdx.x;
  const int q    = nwg >> 3, r = nwg & 7;
  const int xcd  = orig & 7, pos = orig >> 3;
  const int start = (xcd < r) ? xcd * (q + 1) : r * (q + 1) + (xcd - r) * q;
  const int w    = start + pos;
  const int bn   = (w % gridDim.x) << 7;   // N tile: 128
  const int bm   = (w / gridDim.x) << 8;   // M tile: 256

  const __bf16* a0 = A  + (size_t)(bm +       (tid >> 2)) * DMODEL + ((tid & 3) << 3);
  const __bf16* a1 = A  + (size_t)(bm + 128 + (tid >> 2)) * DMODEL + ((tid & 3) << 3);
  const __bf16* b0 = BT + (size_t)(bn +       (tid >> 2)) * DMODEL + ((tid & 3) << 3);

  const int wm = (wid >> 1) << 6;   // 0,64,128,192
  const int wn = (wid & 1) << 6;    // 0,64
  const int lrow = lane & 15;
  const int lk8  = (lane >> 4) << 3;

  f32x4 acc[4][4] = {};   // acc[j][i]: j = channel frag, i = token frag

  // prologue: 2 stages in flight (6 gloads)
  {
    gload_lds16(a0, &As[0][(wid << 9)]);
    gload_lds16(a1, &As[0][4096 + (wid << 9)]);
    gload_lds16(b0, &Bs[0][(wid << 9)]);
    gload_lds16(a0 + 32, &As[1][(wid << 9)]);
    gload_lds16(a1 + 32, &As[1][4096 + (wid << 9)]);
    gload_lds16(b0 + 32, &Bs[1][(wid << 9)]);
  }
  asm volatile("s_waitcnt vmcnt(3)" ::: "memory");   // stage(0) landed
  __builtin_amdgcn_sched_barrier(0);
  __builtin_amdgcn_s_barrier();
  __builtin_amdgcn_sched_barrier(0);

#pragma unroll 1
  for (int kt = 0; kt < 12; ++kt) {
    const int buf = kt % 3;
    const int dst = (kt + 2) % 3;
    // tail wrap: write already-consumed buffers, never read (uniform vmcnt)
    const int nt  = (kt + 2 < 12) ? (kt + 2) : (kt - 10);
    const int koff = nt << 5;
    const __bf16* pA = &As[buf][(wm + lrow) * 32 + lk8];
    const __bf16* pB = &Bs[buf][(wn + lrow) * 32 + lk8];

    // ---- phase 0: 2 A-stage issues | B frags + A frags 0,1 | 8 MFMA ----
    gload_lds16(a0 + koff, &As[dst][(wid << 9)]);
    gload_lds16(a1 + koff, &As[dst][4096 + (wid << 9)]);
    bf16x8 bv[4], av0, av1;
#pragma unroll
    for (int j = 0; j < 4; ++j) bv[j] = *(const bf16x8*)(pB + j * 16 * 32);
    av0 = *(const bf16x8*)(pA);
    av1 = *(const bf16x8*)(pA + 16 * 32);
    __builtin_amdgcn_s_setprio(1);
#pragma unroll
    for (int j = 0; j < 4; ++j)
      acc[j][0] = __builtin_amdgcn_mfma_f32_16x16x32_bf16(bv[j], av0, acc[j][0], 0, 0, 0);
#pragma unroll
    for (int j = 0; j < 4; ++j)
      acc[j][1] = __builtin_amdgcn_mfma_f32_16x16x32_bf16(bv[j], av1, acc[j][1], 0, 0, 0);
    __builtin_amdgcn_s_setprio(0);
    __builtin_amdgcn_sched_barrier(0);
    __builtin_amdgcn_s_barrier();
    __builtin_amdgcn_sched_barrier(0);

    // ---- phase 1: B-stage issue | A frags 2,3 | 8 MFMA | vmcnt(3) ----
    gload_lds16(b0 + koff, &Bs[dst][(wid << 9)]);
    bf16x8 av2, av3;
    av2 = *(const bf16x8*)(pA + 2 * 16 * 32);
    av3 = *(const bf16x8*)(pA + 3 * 16 * 32);
    __builtin_amdgcn_s_setprio(1);
#pragma unroll
    for (int j = 0; j < 4; ++j)
      acc[j][2] = __builtin_amdgcn_mfma_f32_16x16x32_bf16(bv[j], av2, acc[j][2], 0, 0, 0);
#pragma unroll
    for (int j = 0; j < 4; ++j)
      acc[j][3] = __builtin_amdgcn_mfma_f32_16x16x32_bf16(bv[j], av3, acc[j][3], 0, 0, 0);
    __builtin_amdgcn_s_setprio(0);
    __builtin_amdgcn_sched_barrier(0);
    asm volatile("s_waitcnt vmcnt(3)" ::: "memory");   // stage(kt+1) landed
    __builtin_amdgcn_sched_barrier(0);
    __builtin_amdgcn_s_barrier();
    __builtin_amdgcn_sched_barrier(0);
  }

  const int lr = lane & 15, g = lane >> 4;
  const int tok0 = bm + wm + lr;
  const int ch0  = bn + wn + (g << 2);

#pragma unroll
  for (int j = 0; j < 4; ++j) {
    const int ch = ch0 + 16 * j;
    const float4 b4 = *(const float4*)&bias[ch];
#pragma unroll
    for (int i = 0; i < 4; ++i) {
      const int token = tok0 + 16 * i;
      ushort4 pk;
      pk.x = f2bfu(acc[j][i][0] + b4.x);
      pk.y = f2bfu(acc[j][i][1] + b4.y);
      pk.z = f2bfu(acc[j][i][2] + b4.z);
      pk.w = f2bfu(acc[j][i][3] + b4.w);
      *(ushort4*)&Cout[(size_t)token * Ncols + ch] = pk;
    }
  }
}

// ---------------------------------------------------------------------------
// MFMA attention: one wave per (window, head). Pad 49 -> 64. (unchanged)
// ---------------------------------------------------------------------------
__global__ __launch_bounds__(64) void attn_mfma(const __bf16* __restrict__ qkv,
                                                __bf16* __restrict__ attnO) {
  __shared__ __align__(16) __bf16 lds[96 * 72];
  __bf16* p_lds = lds;
  __bf16* vt    = lds + 64 * 72;

  const int lane = threadIdx.x;
  const int win  = blockIdx.x;
  const int h    = blockIdx.y;
  const int lr = lane & 15, g = lane >> 4;
  const size_t rowbase = (size_t)win * 49;

  int rr[4];
#pragma unroll
  for (int f = 0; f < 4; ++f) rr[f] = (16 * f + lr > 48) ? 48 : (16 * f + lr);

  const int co = h * 32 + 8 * g;

  bf16x8 av[4], bv[4];
#pragma unroll
  for (int f = 0; f < 4; ++f) {
    const __bf16* rp = qkv + (rowbase + rr[f]) * NQKV + co;
    av[f] = *(const bf16x8*)(rp + 384);
    bv[f] = *(const bf16x8*)(rp);
  }

  ushort4 vreg[7];
#pragma unroll
  for (int u = 0; u < 7; ++u) {
    const int unit = lane + (u << 6);
    if (unit < 392) {
      const int k = unit >> 3, dq = unit & 7;
      vreg[u] = *(const ushort4*)(qkv + (rowbase + k) * NQKV + 768 + h * 32 + 4 * dq);
    }
  }

  f32x4 acc[4][4] = {};
#pragma unroll
  for (int i = 0; i < 4; ++i)
#pragma unroll
    for (int j = 0; j < 4; ++j)
      acc[i][j] = __builtin_amdgcn_mfma_f32_16x16x32_bf16(av[i], bv[j], acc[i][j], 0, 0, 0);

  const float scale = 0.17677669529663687f;
#pragma unroll
  for (int i = 0; i < 4; ++i)
#pragma unroll
    for (int j = 0; j < 4; ++j)
#pragma unroll
      for (int r = 0; r < 4; ++r) {
        float v = acc[i][j][r] * scale;
        if (i == 3 && (4 * g + r) != 0) v = -1e30f;
        acc[i][j][r] = v;
      }

#pragma unroll
  for (int u = 0; u < 7; ++u) {
    const int unit = lane + (u << 6);
    if (unit < 392) {
      const int k = unit >> 3, dq = unit & 7;
      const ushort4 vv = vreg[u];
      vt[(4 * dq + 0) * 72 + k] = __builtin_bit_cast(__bf16, vv.x);
      vt[(4 * dq + 1) * 72 + k] = __builtin_bit_cast(__bf16, vv.y);
      vt[(4 * dq + 2) * 72 + k] = __builtin_bit_cast(__bf16, vv.z);
      vt[(4 * dq + 3) * 72 + k] = __builtin_bit_cast(__bf16, vv.w);
    }
  }

#pragma unroll
  for (int j = 0; j < 4; ++j) {
    float mx = -1e30f;
#pragma unroll
    for (int i = 0; i < 4; ++i)
#pragma unroll
      for (int r = 0; r < 4; ++r) mx = fmaxf(mx, acc[i][j][r]);
    mx = fmaxf(mx, __shfl_xor(mx, 16));
    mx = fmaxf(mx, __shfl_xor(mx, 32));
    float sum = 0.f;
#pragma unroll
    for (int i = 0; i < 4; ++i)
#pragma unroll
      for (int r = 0; r < 4; ++r) {
        const float e = __expf(acc[i][j][r] - mx);
        acc[i][j][r] = e;
        sum += e;
      }
    sum += __shfl_xor(sum, 16);
    sum += __shfl_xor(sum, 32);
    const float inv = 1.f / sum;
#pragma unroll
    for (int i = 0; i < 4; ++i) {
      ushort4 pk;
      pk.x = f2bfu(acc[i][j][0] * inv);
      pk.y = f2bfu(acc[i][j][1] * inv);
      pk.z = f2bfu(acc[i][j][2] * inv);
      pk.w = f2bfu(acc[i][j][3] * inv);
      *(ushort4*)&p_lds[(16 * j + lr) * 72 + 16 * i + 4 * g] = pk;
    }
  }

  f32x4 o[2][4] = {};
#pragma unroll
  for (int ks = 0; ks < 2; ++ks) {
    bf16x8 a2[2], b2[4];
#pragma unroll
    for (int i2 = 0; i2 < 2; ++i2)
      a2[i2] = *(const bf16x8*)&vt[(16 * i2 + lr) * 72 + 32 * ks + 8 * g];
#pragma unroll
    for (int j2 = 0; j2 < 4; ++j2)
      b2[j2] = *(const bf16x8*)&p_lds[(16 * j2 + lr) * 72 + 32 * ks + 8 * g];
#pragma unroll
    for (int i2 = 0; i2 < 2; ++i2)
#pragma unroll
      for (int j2 = 0; j2 < 4; ++j2)
        o[i2][j2] = __builtin_amdgcn_mfma_f32_16x16x32_bf16(a2[i2], b2[j2], o[i2][j2], 0, 0, 0);
  }

#pragma unroll
  for (int j2 = 0; j2 < 4; ++j2) {
    const int q = 16 * j2 + lr;
    if (q <= 48) {
#pragma unroll
      for (int i2 = 0; i2 < 2; ++i2) {
        ushort4 ok;
        ok.x = f2bfu(o[i2][j2][0]);
        ok.y = f2bfu(o[i2][j2][1]);
        ok.z = f2bfu(o[i2][j2][2]);
        ok.w = f2bfu(o[i2][j2][3]);
        *(ushort4*)&attnO[(rowbase + q) * DMODEL + h * 32 + 16 * i2 + 4 * g] = ok;
      }
    }
  }
}

extern "C" void kernel_launch(void* const* d_in, const int* in_sizes, int n_in,
                              void* d_out, int out_size, void* d_ws, size_t ws_size,
                              hipStream_t stream) {
  const float* x     = (const float*)d_in[0];
  const float* Wqkv  = (const float*)d_in[1];
  const float* bqkv  = (const float*)d_in[2];
  const float* Wproj = (const float*)d_in[3];
  const float* bproj = (const float*)d_in[4];
  float* out = (float*)d_out;

  char* ws = (char*)d_ws;
  __bf16* Xw     = (__bf16*)ws;  ws += (size_t)TOK * DMODEL * 2;   // 38.5 MB
  __bf16* qkvb   = (__bf16*)ws;  ws += (size_t)TOK * NQKV * 2;     // 115.6 MB
  __bf16* attnO  = (__bf16*)ws;  ws += (size_t)TOK * DMODEL * 2;   // 38.5 MB
  __bf16* attnP  = (__bf16*)ws;  ws += (size_t)TOK * DMODEL * 2;   // 38.5 MB
  __bf16* WqkvT  = (__bf16*)ws;  ws += (size_t)NQKV * DMODEL * 2;
  __bf16* WprojT = (__bf16*)ws;

  gather_x<<<dim3(8, 8, 16), 256, 0, stream>>>(x, Xw);
  conv_w<<<1728, 256, 0, stream>>>(Wqkv, Wproj, WqkvT, WprojT);
  gemm256<<<dim3(NQKV / 128, TOK / 256), 512, 0, stream>>>(Xw, WqkvT, bqkv, qkvb, NQKV);
  attn_mfma<<<dim3(NWIN, 12), 64, 0, stream>>>(qkvb, attnO);
  gemm256<<<dim3(DMODEL / 128, TOK / 256), 512, 0, stream>>>(attnO, WprojT, bproj, attnP, DMODEL);
  unscatter<<<dim3(8, 8, 16), 256, 0, stream>>>(attnP, out);
}